// Round 1
// baseline (1328.184 us; speedup 1.0000x reference)
//
#include <hip/hip_runtime.h>
#include <hip/hip_fp16.h>

// ---------------------------------------------------------------------------
// Heads: per-head QKV projections + causal attention, B=4 T=1024 C=1024 H=8.
// Round 1: correctness-first pipeline, m97-style 128x128 MFMA GEMM (fp16 in,
// fp32 acc). Per-head processing keeps workspace at 70 MB.
// ---------------------------------------------------------------------------

typedef unsigned short u16;
typedef _Float16 f16x8 __attribute__((ext_vector_type(8)));
typedef float f32x4 __attribute__((ext_vector_type(4)));

__device__ __forceinline__ u16 f2h(float f) {
    union { __half h; u16 u; } cv;
    cv.h = __float2half(f);
    return cv.u;
}

// global -> LDS direct copy, 16B per lane. LDS dest is wave-uniform base +
// lane*16 (HW behavior). CK-style address-space casts.
__device__ __forceinline__ void gload_lds16(const void* g, char* lds_base, unsigned off) {
    unsigned a32 = (unsigned)(uintptr_t)(lds_base + off);
    a32 = __builtin_amdgcn_readfirstlane(a32);
    __builtin_amdgcn_global_load_lds(
        (const __attribute__((address_space(1))) void*)(uintptr_t)g,
        (__attribute__((address_space(3))) void*)a32,
        16, 0, 0);
}

// ---------------------------------------------------------------------------
// gemm_bt: D[m,n] = scale * sum_k A[m,k] * Bt[n,k]   (B given transposed)
// 128x128 tile, BK=32, 256 threads = 4 waves in 2x2, each wave 64x64 (4x4
// frags of 16x16x32 MFMA). OM: 0 = fp16 out, 1 = fp32 out, 2 = fp32 out +
// causal tile skip (requires square tile grid).
// ---------------------------------------------------------------------------
template <int OM>
__global__ __launch_bounds__(256) void gemm_bt(
    const u16* __restrict__ A, const u16* __restrict__ Bt, void* __restrict__ Cout,
    int lda, int ldb, int ldc, long sA, long sB, long sC, int K, float scale)
{
    const int tile_n = blockIdx.x, tile_m = blockIdx.y, bz = blockIdx.z;
    if (OM == 2 && tile_n > tile_m) return;  // causal: skip upper-tri tiles

    const u16* Ab = A + (size_t)bz * sA;
    const u16* Bb = Bt + (size_t)bz * sB;

    __shared__ u16 lA[128 * 32];
    __shared__ u16 lB[128 * 32];

    const int t = threadIdx.x, w = t >> 6, l = t & 63;
    const int m0 = tile_m * 128, n0 = tile_n * 128;
    const int wm = (w >> 1) * 64, wn = (w & 1) * 64;
    const int frow = l & 15, fk = (l >> 4) * 8;

    f32x4 acc[4][4] = {};

    for (int k0 = 0; k0 < K; k0 += 32) {
        // stage A tile [128 rows x 32 cols] row-major; 512 chunks of 16B
#pragma unroll
        for (int i = 0; i < 2; ++i) {
            int chunk = i * 256 + w * 64 + l;     // lane-ordered within wave
            int row = chunk >> 2, cb = chunk & 3; // 4 chunks per 64B row
            gload_lds16(Ab + (size_t)(m0 + row) * lda + k0 + cb * 8,
                        (char*)lA, (unsigned)((i * 256 + w * 64) * 16));
        }
#pragma unroll
        for (int i = 0; i < 2; ++i) {
            int chunk = i * 256 + w * 64 + l;
            int row = chunk >> 2, cb = chunk & 3;
            gload_lds16(Bb + (size_t)(n0 + row) * ldb + k0 + cb * 8,
                        (char*)lB, (unsigned)((i * 256 + w * 64) * 16));
        }
        __syncthreads();  // compiler emits vmcnt(0) before barrier

        f16x8 af[4], bf[4];
#pragma unroll
        for (int mi = 0; mi < 4; ++mi)
            af[mi] = *(const f16x8*)&lA[(wm + mi * 16 + frow) * 32 + fk];
#pragma unroll
        for (int ni = 0; ni < 4; ++ni)
            bf[ni] = *(const f16x8*)&lB[(wn + ni * 16 + frow) * 32 + fk];

#pragma unroll
        for (int mi = 0; mi < 4; ++mi)
#pragma unroll
            for (int ni = 0; ni < 4; ++ni)
                acc[mi][ni] = __builtin_amdgcn_mfma_f32_16x16x32_f16(
                    af[mi], bf[ni], acc[mi][ni], 0, 0, 0);
        __syncthreads();
    }

    // epilogue: C/D layout col = l&15, row = (l>>4)*4 + r
    const int r0 = (l >> 4) * 4, cc = l & 15;
    const size_t cb_off = (size_t)bz * sC;
#pragma unroll
    for (int mi = 0; mi < 4; ++mi) {
#pragma unroll
        for (int r = 0; r < 4; ++r) {
            size_t grow = (size_t)(m0 + wm + mi * 16 + r0 + r);
#pragma unroll
            for (int ni = 0; ni < 4; ++ni) {
                int gcol = n0 + wn + ni * 16 + cc;
                float v = acc[mi][ni][r] * scale;
                if (OM == 0)
                    ((u16*)Cout)[cb_off + grow * ldc + gcol] = f2h(v);
                else
                    ((float*)Cout)[cb_off + grow * ldc + gcol] = v;
            }
        }
    }
}

// ---------------------------------------------------------------------------
// row-wise causal softmax: S fp32 [B, T, T] -> P fp16 [B, T, T]
// row t: softmax over cols 0..t (scale already applied in QK epilogue),
// cols t+1..T-1 zero-filled so PV can run as a plain full-K GEMM.
// ---------------------------------------------------------------------------
__global__ __launch_bounds__(256) void softmax_causal(
    const float* __restrict__ S, u16* __restrict__ P, int T)
{
    const int t = blockIdx.x, b = blockIdx.y;
    const float* row = S + ((size_t)b * T + t) * T;
    u16* prow = P + ((size_t)b * T + t) * T;
    const int n = t + 1, tid = threadIdx.x;

    float lmax = -3.0e38f;
    for (int i = tid; i < n; i += 256) lmax = fmaxf(lmax, row[i]);
    for (int o = 32; o; o >>= 1) lmax = fmaxf(lmax, __shfl_down(lmax, o));
    __shared__ float red[4];
    if ((tid & 63) == 0) red[tid >> 6] = lmax;
    __syncthreads();
    const float m = fmaxf(fmaxf(red[0], red[1]), fmaxf(red[2], red[3]));

    float ls = 0.f;
    for (int i = tid; i < n; i += 256) ls += expf(row[i] - m);
    for (int o = 32; o; o >>= 1) ls += __shfl_down(ls, o);
    __shared__ float red2[4];
    if ((tid & 63) == 0) red2[tid >> 6] = ls;
    __syncthreads();
    const float inv = 1.0f / (red2[0] + red2[1] + red2[2] + red2[3]);

    for (int i = tid; i < T; i += 256) {
        float p = (i < n) ? expf(row[i] - m) * inv : 0.f;
        prow[i] = f2h(p);
    }
}

// V [T, C] -> VT [C, T] per batch (blockIdx.z), 32x32 LDS tiles, +1 pad
__global__ void transpose_f16(const u16* __restrict__ V, u16* __restrict__ VT,
                              int rows, int cols)
{
    __shared__ u16 tile[32][33];
    const int c0 = blockIdx.x * 32, t0 = blockIdx.y * 32;
    const size_t zb = (size_t)blockIdx.z * rows * cols;
    const int x = threadIdx.x, y = threadIdx.y;  // (32, 8)
    for (int i = y; i < 32; i += 8)
        tile[i][x] = V[zb + (size_t)(t0 + i) * cols + c0 + x];
    __syncthreads();
    for (int i = y; i < 32; i += 8)
        VT[zb + (size_t)(c0 + i) * rows + t0 + x] = tile[x][i];
}

__global__ void cast_f32_f16(const float* __restrict__ src, u16* __restrict__ dst, int n4)
{
    int i = blockIdx.x * 256 + threadIdx.x;
    if (i < n4) {
        float4 v = ((const float4*)src)[i];
        ushort4 o;
        o.x = f2h(v.x); o.y = f2h(v.y); o.z = f2h(v.z); o.w = f2h(v.w);
        ((ushort4*)dst)[i] = o;
    }
}

extern "C" void kernel_launch(void* const* d_in, const int* in_sizes, int n_in,
                              void* d_out, int out_size, void* d_ws, size_t ws_size,
                              hipStream_t stream)
{
    (void)in_sizes; (void)n_in; (void)out_size; (void)ws_size;
    const int B = 4, T = 1024, C = 1024, H = 8;

    const float* data = (const float*)d_in[0];
    const float* Wq = (const float*)d_in[1];
    const float* Wk = (const float*)d_in[2];
    const float* Wv = (const float*)d_in[3];
    float* out = (float*)d_out;

    // workspace layout (70 MB total)
    char* p = (char*)d_ws;
    const size_t nBTC = (size_t)B * T * C;           // 4M elements
    u16* dataH = (u16*)p; p += nBTC * 2;             // 8 MB
    u16* WqH = (u16*)p; p += (size_t)C * C * 2;      // 2 MB (per-head, reused)
    u16* WkH = (u16*)p; p += (size_t)C * C * 2;
    u16* WvH = (u16*)p; p += (size_t)C * C * 2;
    u16* Qh = (u16*)p; p += nBTC * 2;                // 8 MB each
    u16* Kh = (u16*)p; p += nBTC * 2;
    u16* Vh = (u16*)p; p += nBTC * 2;
    u16* VTh = (u16*)p; p += nBTC * 2;
    float* S = (float*)p; p += (size_t)B * T * T * 4; // 16 MB
    u16* P = (u16*)p; p += (size_t)B * T * T * 2;     // 8 MB

    const dim3 blk(256);
    const float inv_sqrt_c = 1.0f / 32.0f;  // 1/sqrt(1024)

    // cast activations once
    cast_f32_f16<<<dim3((unsigned)(nBTC / 4 / 256)), blk, 0, stream>>>(data, dataH, (int)(nBTC / 4));

    for (int h = 0; h < H; ++h) {
        const size_t wo = (size_t)h * C * C;
        cast_f32_f16<<<dim3(1024), blk, 0, stream>>>(Wq + wo, WqH, C * C / 4);
        cast_f32_f16<<<dim3(1024), blk, 0, stream>>>(Wk + wo, WkH, C * C / 4);
        cast_f32_f16<<<dim3(1024), blk, 0, stream>>>(Wv + wo, WvH, C * C / 4);

        // projections: [B*T=4096, C] x W[h]^T -> fp16 [B*T, C]
        gemm_bt<0><<<dim3(C / 128, (B * T) / 128, 1), blk, 0, stream>>>(
            dataH, WqH, Qh, C, C, C, 0, 0, 0, C, 1.0f);
        gemm_bt<0><<<dim3(C / 128, (B * T) / 128, 1), blk, 0, stream>>>(
            dataH, WkH, Kh, C, C, C, 0, 0, 0, C, 1.0f);
        gemm_bt<0><<<dim3(C / 128, (B * T) / 128, 1), blk, 0, stream>>>(
            dataH, WvH, Vh, C, C, C, 0, 0, 0, C, 1.0f);

        // V^T for the PV GEMM's B-operand (wants [N=d][K=s] row-major)
        transpose_f16<<<dim3(C / 32, T / 32, B), dim3(32, 8), 0, stream>>>(Vh, VTh, T, C);

        // scores = Q K^T / sqrt(C), causal tiles only, fp32
        gemm_bt<2><<<dim3(T / 128, T / 128, B), blk, 0, stream>>>(
            Qh, Kh, S, C, C, T, (long)T * C, (long)T * C, (long)T * T, C, inv_sqrt_c);

        softmax_causal<<<dim3(T, B), blk, 0, stream>>>(S, P, T);

        // out[b, t, h*C + d] = sum_s P[t,s] V[s,d]
        gemm_bt<1><<<dim3(C / 128, T / 128, B), blk, 0, stream>>>(
            P, VTh, out + (size_t)h * C, T, T, H * C,
            (long)T * T, (long)C * T, (long)T * H * C, T, 1.0f);
    }
}

// Round 2
// 648.245 us; speedup vs baseline: 2.0489x; 2.0489x over previous
//
#include <hip/hip_runtime.h>
#include <hip/hip_fp16.h>

// ---------------------------------------------------------------------------
// Heads: per-head QKV projections + causal attention, B=4 T=1024 C=1024 H=8.
// Round 2: batch everything across heads. 11 dispatches total:
//   3 casts (W) + 1 cast (data) + 3 proj GEMMs [4096x8192x1024] +
//   1 V-transpose + 1 causal QK^T + 1 softmax + 1 causal-K PV.
// GEMM is the m97-style 128x128 / BK=32 / 4-wave structure (fp16 in, fp32 acc).
// ---------------------------------------------------------------------------

typedef unsigned short u16;
typedef _Float16 f16x8 __attribute__((ext_vector_type(8)));
typedef float f32x4 __attribute__((ext_vector_type(4)));

__device__ __forceinline__ u16 f2h(float f) {
    union { __half h; u16 u; } cv;
    cv.h = __float2half(f);
    return cv.u;
}

// global -> LDS direct copy, 16B per lane (wave-uniform LDS base + lane*16).
__device__ __forceinline__ void gload_lds16(const void* g, char* lds_base, unsigned off) {
    unsigned a32 = (unsigned)(uintptr_t)(lds_base + off);
    a32 = __builtin_amdgcn_readfirstlane(a32);
    __builtin_amdgcn_global_load_lds(
        (const __attribute__((address_space(1))) void*)(uintptr_t)g,
        (__attribute__((address_space(3))) void*)a32,
        16, 0, 0);
}

// ---------------------------------------------------------------------------
// gemm_bt: D[m,n] = scale * sum_k A[m,k] * Bt[n,k]   (B given row-major [N,K])
// z-batched: per blockIdx.z offsets are (z>>3)*hi + (z&7)*lo (H=8 hardcoded).
// OM: 0 = fp16 out
//     1 = fp32 out
//     2 = fp32 out + causal tile skip (QK^T; square tile grid)
//     3 = fp32 out + causal K-limit (PV; K_eff = m0+128)
// ---------------------------------------------------------------------------
template <int OM>
__global__ __launch_bounds__(256) void gemm_bt(
    const u16* __restrict__ A, const u16* __restrict__ Bt, void* __restrict__ Cout,
    int lda, int ldb, int ldc,
    long sA_hi, long sA_lo, long sB_hi, long sB_lo, long sC_hi, long sC_lo,
    int K, float scale)
{
    const int tile_n = blockIdx.x, tile_m = blockIdx.y, z = blockIdx.z;
    if (OM == 2 && tile_n > tile_m) return;  // causal: skip upper-tri tiles

    const int zh = z >> 3, zl = z & 7;
    const u16* Ab = A + (size_t)zh * sA_hi + (size_t)zl * sA_lo;
    const u16* Bb = Bt + (size_t)zh * sB_hi + (size_t)zl * sB_lo;

    __shared__ u16 lA[128 * 32];
    __shared__ u16 lB[128 * 32];

    const int t = threadIdx.x, w = t >> 6, l = t & 63;
    const int m0 = tile_m * 128, n0 = tile_n * 128;
    const int wm = (w >> 1) * 64, wn = (w & 1) * 64;
    const int frow = l & 15, fk = (l >> 4) * 8;

    const int Kend = (OM == 3) ? min(K, m0 + 128) : K;

    f32x4 acc[4][4] = {};

    for (int k0 = 0; k0 < Kend; k0 += 32) {
        // stage A/B tiles [128 rows x 32 cols] row-major; 512 chunks of 16B each
#pragma unroll
        for (int i = 0; i < 2; ++i) {
            int chunk = i * 256 + w * 64 + l;
            int row = chunk >> 2, cb = chunk & 3;
            gload_lds16(Ab + (size_t)(m0 + row) * lda + k0 + cb * 8,
                        (char*)lA, (unsigned)((i * 256 + w * 64) * 16));
        }
#pragma unroll
        for (int i = 0; i < 2; ++i) {
            int chunk = i * 256 + w * 64 + l;
            int row = chunk >> 2, cb = chunk & 3;
            gload_lds16(Bb + (size_t)(n0 + row) * ldb + k0 + cb * 8,
                        (char*)lB, (unsigned)((i * 256 + w * 64) * 16));
        }
        __syncthreads();

        f16x8 af[4], bf[4];
#pragma unroll
        for (int mi = 0; mi < 4; ++mi)
            af[mi] = *(const f16x8*)&lA[(wm + mi * 16 + frow) * 32 + fk];
#pragma unroll
        for (int ni = 0; ni < 4; ++ni)
            bf[ni] = *(const f16x8*)&lB[(wn + ni * 16 + frow) * 32 + fk];

#pragma unroll
        for (int mi = 0; mi < 4; ++mi)
#pragma unroll
            for (int ni = 0; ni < 4; ++ni)
                acc[mi][ni] = __builtin_amdgcn_mfma_f32_16x16x32_f16(
                    af[mi], bf[ni], acc[mi][ni], 0, 0, 0);
        __syncthreads();
    }

    // epilogue: C/D layout col = l&15, row = (l>>4)*4 + r
    const int r0 = (l >> 4) * 4, cc = l & 15;
    const size_t cb_off = (size_t)zh * sC_hi + (size_t)zl * sC_lo;
#pragma unroll
    for (int mi = 0; mi < 4; ++mi) {
#pragma unroll
        for (int r = 0; r < 4; ++r) {
            size_t grow = (size_t)(m0 + wm + mi * 16 + r0 + r);
#pragma unroll
            for (int ni = 0; ni < 4; ++ni) {
                int gcol = n0 + wn + ni * 16 + cc;
                float v = acc[mi][ni][r] * scale;
                if (OM == 0)
                    ((u16*)Cout)[cb_off + grow * ldc + gcol] = f2h(v);
                else
                    ((float*)Cout)[cb_off + grow * ldc + gcol] = v;
            }
        }
    }
}

// ---------------------------------------------------------------------------
// row-wise causal softmax: S fp32 [Z, T, T] -> P fp16 [Z, T, T]
// row t: softmax over cols 0..t; zero-fill only out to round128(t+1) (PV's
// causal K-limit never reads beyond that).
// ---------------------------------------------------------------------------
__global__ __launch_bounds__(256) void softmax_causal(
    const float* __restrict__ S, u16* __restrict__ P, int T)
{
    const int t = blockIdx.x, z = blockIdx.y;
    const float* row = S + ((size_t)z * T + t) * T;
    u16* prow = P + ((size_t)z * T + t) * T;
    const int n = t + 1, tid = threadIdx.x;
    const int nw = ((t >> 7) + 1) << 7;  // write limit (128-rounded)

    float lmax = -3.0e38f;
    for (int i = tid; i < n; i += 256) lmax = fmaxf(lmax, row[i]);
    for (int o = 32; o; o >>= 1) lmax = fmaxf(lmax, __shfl_down(lmax, o));
    __shared__ float red[4];
    if ((tid & 63) == 0) red[tid >> 6] = lmax;
    __syncthreads();
    const float m = fmaxf(fmaxf(red[0], red[1]), fmaxf(red[2], red[3]));

    float ls = 0.f;
    for (int i = tid; i < n; i += 256) ls += expf(row[i] - m);
    for (int o = 32; o; o >>= 1) ls += __shfl_down(ls, o);
    __shared__ float red2[4];
    if ((tid & 63) == 0) red2[tid >> 6] = ls;
    __syncthreads();
    const float inv = 1.0f / (red2[0] + red2[1] + red2[2] + red2[3]);

    for (int i = tid; i < nw; i += 256) {
        float p = (i < n) ? expf(row[i] - m) * inv : 0.f;
        prow[i] = f2h(p);
    }
}

// V_all [4096, 8192] (row b*T+t, col h*C+c) -> VT [Z=32, C=1024, T=1024]
__global__ void transpose_f16(const u16* __restrict__ V, u16* __restrict__ VT)
{
    __shared__ u16 tile[32][33];
    const int z = blockIdx.z, b = z >> 3, h = z & 7;
    const u16* src = V + (size_t)b * 1024 * 8192 + (size_t)h * 1024;
    u16* dst = VT + (size_t)z * 1024 * 1024;
    const int c0 = blockIdx.x * 32, t0 = blockIdx.y * 32;
    const int x = threadIdx.x, y = threadIdx.y;  // (32, 8)
    for (int i = y; i < 32; i += 8)
        tile[i][x] = src[(size_t)(t0 + i) * 8192 + c0 + x];
    __syncthreads();
    for (int i = y; i < 32; i += 8)
        dst[(size_t)(c0 + i) * 1024 + t0 + x] = tile[x][i];
}

__global__ void cast_f32_f16(const float* __restrict__ src, u16* __restrict__ dst, int n4)
{
    int i = blockIdx.x * 256 + threadIdx.x;
    if (i < n4) {
        float4 v = ((const float4*)src)[i];
        ushort4 o;
        o.x = f2h(v.x); o.y = f2h(v.y); o.z = f2h(v.z); o.w = f2h(v.w);
        ((ushort4*)dst)[i] = o;
    }
}

extern "C" void kernel_launch(void* const* d_in, const int* in_sizes, int n_in,
                              void* d_out, int out_size, void* d_ws, size_t ws_size,
                              hipStream_t stream)
{
    (void)in_sizes; (void)n_in; (void)out_size; (void)ws_size;
    const int B = 4, T = 1024, C = 1024, H = 8;
    const int BT = B * T;          // 4096
    const int HC = H * C;          // 8192

    const float* data = (const float*)d_in[0];
    const float* Wq = (const float*)d_in[1];
    const float* Wk = (const float*)d_in[2];
    const float* Wv = (const float*)d_in[3];
    float* out = (float*)d_out;

    // workspace layout (504 MiB total; ws is 512 MiB per harness poison fill)
    char* p = (char*)d_ws;
    const size_t nData = (size_t)BT * C;     // 4M
    const size_t nW = (size_t)H * C * C;     // 8M
    const size_t nAll = (size_t)BT * HC;     // 32M
    const size_t nS = (size_t)B * H * T * T; // 32M
    u16* dataH = (u16*)p; p += nData * 2;    //   8 MiB
    u16* WqH = (u16*)p; p += nW * 2;         //  16 MiB
    u16* WkH = (u16*)p; p += nW * 2;         //  16 MiB
    u16* WvH = (u16*)p; p += nW * 2;         //  16 MiB
    u16* Qa = (u16*)p; p += nAll * 2;        //  64 MiB
    u16* Ka = (u16*)p; p += nAll * 2;        //  64 MiB
    u16* Va = (u16*)p; p += nAll * 2;        //  64 MiB
    u16* VTa = (u16*)p; p += nAll * 2;       //  64 MiB
    float* S = (float*)p; p += nS * 4;       // 128 MiB
    u16* P = (u16*)p; p += nS * 2;           //  64 MiB

    const dim3 blk(256);
    const float inv_sqrt_c = 1.0f / 32.0f;   // 1/sqrt(1024)

    // casts
    cast_f32_f16<<<dim3((unsigned)(nData / 4 / 256)), blk, 0, stream>>>(data, dataH, (int)(nData / 4));
    cast_f32_f16<<<dim3((unsigned)(nW / 4 / 256)), blk, 0, stream>>>(Wq, WqH, (int)(nW / 4));
    cast_f32_f16<<<dim3((unsigned)(nW / 4 / 256)), blk, 0, stream>>>(Wk, WkH, (int)(nW / 4));
    cast_f32_f16<<<dim3((unsigned)(nW / 4 / 256)), blk, 0, stream>>>(Wv, WvH, (int)(nW / 4));

    // projections, all heads at once: [4096, 1024] x [8192, 1024]^T -> [4096, 8192]
    gemm_bt<0><<<dim3(HC / 128, BT / 128, 1), blk, 0, stream>>>(
        dataH, WqH, Qa, C, C, HC, 0, 0, 0, 0, 0, 0, C, 1.0f);
    gemm_bt<0><<<dim3(HC / 128, BT / 128, 1), blk, 0, stream>>>(
        dataH, WkH, Ka, C, C, HC, 0, 0, 0, 0, 0, 0, C, 1.0f);
    gemm_bt<0><<<dim3(HC / 128, BT / 128, 1), blk, 0, stream>>>(
        dataH, WvH, Va, C, C, HC, 0, 0, 0, 0, 0, 0, C, 1.0f);

    // V^T per (b,h): [C, T], z-major layout
    transpose_f16<<<dim3(C / 32, T / 32, B * H), dim3(32, 8), 0, stream>>>(Va, VTa);

    // scores = Q K^T / sqrt(C), causal tiles only, fp32. z = b*8+h
    gemm_bt<2><<<dim3(T / 128, T / 128, B * H), blk, 0, stream>>>(
        Qa, Ka, S,
        HC, HC, T,
        (long)T * HC, C,              // A (Qa): b-stride, h-stride
        (long)T * HC, C,              // B (Ka)
        (long)H * T * T, (long)T * T, // C (S): z-major
        C, inv_sqrt_c);

    softmax_causal<<<dim3(T, B * H), blk, 0, stream>>>(S, P, T);

    // out[b, t, h*C + d] = sum_s P[t,s] V[s,d], causal K-limit
    gemm_bt<3><<<dim3(C / 128, T / 128, B * H), blk, 0, stream>>>(
        P, VTa, out,
        T, T, HC,
        (long)H * T * T, (long)T * T, // A (P)
        (long)H * C * T, (long)C * T, // B (VT)
        (long)T * HC, C,              // C (out): b-stride, h-stride
        T, 1.0f);
}

// Round 3
// 472.928 us; speedup vs baseline: 2.8084x; 1.3707x over previous
//
#include <hip/hip_runtime.h>
#include <hip/hip_fp16.h>

// ---------------------------------------------------------------------------
// Heads: per-head QKV projections + causal attention, B=4 T=1024 C=1024 H=8.
// Round 3: 256x256 8-phase counted-vmcnt GEMM (guide §5 template, T2+T3+T4+T5)
// for all matmuls. BK=64, K-half (16KB) staging units, double-buffered.
// 10 dispatches: 4 casts + Q/K proj + VT proj + causal QK^T + softmax + PV.
// ---------------------------------------------------------------------------

typedef unsigned short u16;
typedef _Float16 f16x8 __attribute__((ext_vector_type(8)));
typedef float f32x4 __attribute__((ext_vector_type(4)));

__device__ __forceinline__ u16 f2h(float f) {
    union { __half h; u16 u; } cv;
    cv.h = __float2half(f);
    return cv.u;
}

// global -> LDS direct copy, 16B/lane (wave-uniform LDS base + lane*16).
__device__ __forceinline__ void gload_lds16(const u16* g, const u16* lds_base, unsigned off_bytes) {
    unsigned a32 = (unsigned)(uintptr_t)((const char*)lds_base + off_bytes);
    a32 = __builtin_amdgcn_readfirstlane(a32);
    __builtin_amdgcn_global_load_lds(
        (const __attribute__((address_space(1))) void*)(uintptr_t)g,
        (__attribute__((address_space(3))) void*)a32,
        16, 0, 0);
}

// ---------------------------------------------------------------------------
// gemm256: D[m,n] = scale * sum_k A[m,k] * Bt[n,k]  (both operands [rows][K])
// 256x256 tile, BK=64, 512 threads = 8 waves (2M x 4N), per-wave 128x64 out.
// LDS: [dbuf 2][mat 2][khalf 2] x (256 rows x 32 cols fp16 = 16KB) = 128 KB.
// Swizzle (T2): byte ^= ((row>>1)&3)<<4  (2-way residual, free).
// OM: 0 = fp16 out, 2 = fp32 out + causal tile skip, 3 = fp32 + causal K-limit.
// z-batch: offsets (z>>3)*hi + (z&7)*lo.
// ---------------------------------------------------------------------------
template <int OM>
__global__ __launch_bounds__(512, 2) void gemm256(
    const u16* __restrict__ A, const u16* __restrict__ Bt, void* __restrict__ Cout,
    int lda, int ldb, int ldc,
    long sA_hi, long sA_lo, long sB_hi, long sB_lo, long sC_hi, long sC_lo,
    int K, float scale)
{
    const int tile_n = blockIdx.x, tile_m = blockIdx.y, z = blockIdx.z;
    if (OM == 2 && tile_n > tile_m) return;  // causal: skip upper-tri tiles

    const int zh = z >> 3, zl = z & 7;
    const u16* Ab = A + (size_t)zh * sA_hi + (size_t)zl * sA_lo + (size_t)tile_m * 256 * lda;
    const u16* Bb = Bt + (size_t)zh * sB_hi + (size_t)zl * sB_lo + (size_t)tile_n * 256 * ldb;

    __shared__ u16 lds[8 * 8192];  // halfbase(db,mat,ks) = ((db<<2)|(mat<<1)|ks)*8192

    const int t = threadIdx.x, w = t >> 6, l = t & 63;
    const int wm = w >> 2, wn = w & 3;
    const int frow = l & 15, fch = l >> 4;

    const int Kend = (OM == 3) ? min(K, (tile_m + 1) * 256) : K;
    const int NT = Kend / 64;  // even, >= 4 at all call sites

    // staging constants: linear chunk clin -> logical (row, chunk) via involution
    const int clin = w * 64 + l;
    const int srow = clin >> 2;
    const int sch = (clin & 3) ^ ((clin >> 3) & 3);
    const long eA = (long)srow * lda + sch * 8;
    const long eB = (long)srow * ldb + sch * 8;

    f32x4 acc[8][4] = {};
    f16x8 af[4], bf[4];

    // STAGE one K-half (16KB): mat 0=A 1=B, ks 0/1, tile tt, dbuf db
#define STAGE(DB, MAT, KS, TT) do {                                            \
        const u16* g_ = (MAT == 0 ? Ab + (size_t)(TT) * 64 + (KS) * 32 + eA    \
                                  : Bb + (size_t)(TT) * 64 + (KS) * 32 + eB);  \
        const u16* hb_ = lds + ((((DB) << 2) | ((MAT) << 1) | (KS)) << 13);    \
        gload_lds16(g_, hb_, (unsigned)(w * 64 * 16));                         \
        gload_lds16(g_ + (size_t)128 * (MAT == 0 ? lda : ldb), hb_,            \
                    (unsigned)((512 + w * 64) * 16));                          \
    } while (0)

    // swizzled fragment read
#define RD(DB, MAT, KS, ROW)                                                   \
    (*(const f16x8*)((const char*)(lds + ((((DB) << 2) | ((MAT) << 1) | (KS)) << 13)) + \
                     ((unsigned)((ROW) * 64 + fch * 16) ^ ((((ROW) >> 1) & 3) << 4))))

#define VM6 asm volatile("s_waitcnt vmcnt(6)" ::: "memory")
#define VM0 asm volatile("s_waitcnt vmcnt(0)" ::: "memory")
#define NOPW ((void)0)

    // one phase: ds-reads | prefetch | bar | lgkm | MFMA quad | wait | bar
#define PH(DB, KS, MH, WAITC, ...) do {                                        \
        if ((MH) == 0) {                                                       \
            _Pragma("unroll") for (int ni = 0; ni < 4; ++ni)                   \
                bf[ni] = RD(DB, 1, KS, wn * 64 + ni * 16 + frow);              \
        }                                                                      \
        _Pragma("unroll") for (int m4 = 0; m4 < 4; ++m4)                       \
            af[m4] = RD(DB, 0, KS, wm * 128 + ((MH) * 4 + m4) * 16 + frow);    \
        __VA_ARGS__;                                                           \
        asm volatile("s_barrier" ::: "memory");                                \
        asm volatile("s_waitcnt lgkmcnt(0)" ::: "memory");                     \
        __builtin_amdgcn_sched_barrier(0);                                     \
        __builtin_amdgcn_s_setprio(1);                                         \
        _Pragma("unroll") for (int m4 = 0; m4 < 4; ++m4)                       \
            _Pragma("unroll") for (int ni = 0; ni < 4; ++ni)                   \
                acc[(MH) * 4 + m4][ni] = __builtin_amdgcn_mfma_f32_16x16x32_f16( \
                    af[m4], bf[ni], acc[(MH) * 4 + m4][ni], 0, 0, 0);          \
        __builtin_amdgcn_s_setprio(0);                                         \
        WAITC;                                                                 \
        asm volatile("s_barrier" ::: "memory");                                \
    } while (0)

    // prologue: tile0 (4 halves) + tile1 (3 halves; A-ks1(1) issued at p0)
    STAGE(0, 1, 0, 0); STAGE(0, 0, 0, 0); STAGE(0, 1, 1, 0); STAGE(0, 0, 1, 0);
    STAGE(1, 1, 0, 1); STAGE(1, 0, 0, 1); STAGE(1, 1, 1, 1);
    VM6;  // tile0's 4 halves landed (last 3 halves = 6 loads outstanding)
    asm volatile("s_barrier" ::: "memory");

    for (int tt = 0; tt < NT; tt += 2) {
        const bool more = (tt + 2) < NT;  // NT even => tt+3 < NT iff tt+2 < NT
        PH(0, 0, 0, NOPW, STAGE(1, 0, 1, tt + 1));              // p0
        PH(0, 0, 1, NOPW, if (more) STAGE(0, 1, 0, tt + 2));    // p1
        PH(0, 1, 0, NOPW, if (more) STAGE(0, 0, 0, tt + 2));    // p2
        PH(0, 1, 1, if (more) VM6; else VM0,
                    if (more) STAGE(0, 1, 1, tt + 2));          // p3: tile t+1 ready
        PH(1, 0, 0, NOPW, if (more) STAGE(0, 0, 1, tt + 2));    // p4
        PH(1, 0, 1, NOPW, if (more) STAGE(1, 1, 0, tt + 3));    // p5
        PH(1, 1, 0, NOPW, if (more) STAGE(1, 0, 0, tt + 3));    // p6
        PH(1, 1, 1, if (more) VM6; else VM0,
                    if (more) STAGE(1, 1, 1, tt + 3));          // p7: tile t+2 ready
    }
#undef PH
#undef RD
#undef STAGE

    // epilogue: C/D layout col = l&15, row = (l>>4)*4 + r
    const int r0 = (l >> 4) * 4, cc = l & 15;
    const size_t cb_off = (size_t)zh * sC_hi + (size_t)zl * sC_lo;
#pragma unroll
    for (int mi = 0; mi < 8; ++mi) {
#pragma unroll
        for (int r = 0; r < 4; ++r) {
            size_t grow = (size_t)(tile_m * 256 + wm * 128 + mi * 16 + r0 + r);
#pragma unroll
            for (int ni = 0; ni < 4; ++ni) {
                int gcol = tile_n * 256 + wn * 64 + ni * 16 + cc;
                float v = acc[mi][ni][r] * scale;
                if (OM == 0)
                    ((u16*)Cout)[cb_off + grow * ldc + gcol] = f2h(v);
                else
                    ((float*)Cout)[cb_off + grow * ldc + gcol] = v;
            }
        }
    }
}

// ---------------------------------------------------------------------------
// single-pass causal softmax, T=1024: S fp32 [Z,T,T] -> P fp16 [Z,T,T]
// row in registers (4 floats/thread); zero-fill to round256(t+1) for PV.
// ---------------------------------------------------------------------------
__global__ __launch_bounds__(256) void softmax_causal(
    const float* __restrict__ S, u16* __restrict__ P)
{
    const int T = 1024;
    const int tq = blockIdx.x, z = blockIdx.y;
    const float* row = S + ((size_t)z * T + tq) * T;
    u16* prow = P + ((size_t)z * T + tq) * T;
    const int n = tq + 1;
    const int nw = ((tq >> 8) + 1) << 8;  // 256-rounded write limit
    const int tid = threadIdx.x;
    const int i0 = tid * 4;

    float4 v = ((const float4*)row)[tid];
    float e0 = (i0 + 0 < n) ? v.x : -1e30f;
    float e1 = (i0 + 1 < n) ? v.y : -1e30f;
    float e2 = (i0 + 2 < n) ? v.z : -1e30f;
    float e3 = (i0 + 3 < n) ? v.w : -1e30f;

    float m = fmaxf(fmaxf(e0, e1), fmaxf(e2, e3));
#pragma unroll
    for (int o = 1; o < 64; o <<= 1) m = fmaxf(m, __shfl_xor(m, o));
    __shared__ float red[4];
    if ((tid & 63) == 0) red[tid >> 6] = m;
    __syncthreads();
    m = fmaxf(fmaxf(red[0], red[1]), fmaxf(red[2], red[3]));

    float p0 = __expf(e0 - m), p1 = __expf(e1 - m);
    float p2 = __expf(e2 - m), p3 = __expf(e3 - m);
    float s = p0 + p1 + p2 + p3;
#pragma unroll
    for (int o = 1; o < 64; o <<= 1) s += __shfl_xor(s, o);
    __shared__ float red2[4];
    if ((tid & 63) == 0) red2[tid >> 6] = s;
    __syncthreads();
    const float inv = 1.0f / (red2[0] + red2[1] + red2[2] + red2[3]);

    if (i0 < nw) {
        ushort4 o4;
        o4.x = f2h(p0 * inv); o4.y = f2h(p1 * inv);
        o4.z = f2h(p2 * inv); o4.w = f2h(p3 * inv);
        ((ushort4*)prow)[tid] = o4;
    }
}

__global__ void cast_f32_f16(const float* __restrict__ src, u16* __restrict__ dst, int n4)
{
    int i = blockIdx.x * 256 + threadIdx.x;
    if (i < n4) {
        float4 v = ((const float4*)src)[i];
        ushort4 o;
        o.x = f2h(v.x); o.y = f2h(v.y); o.z = f2h(v.z); o.w = f2h(v.w);
        ((ushort4*)dst)[i] = o;
    }
}

extern "C" void kernel_launch(void* const* d_in, const int* in_sizes, int n_in,
                              void* d_out, int out_size, void* d_ws, size_t ws_size,
                              hipStream_t stream)
{
    (void)in_sizes; (void)n_in; (void)out_size; (void)ws_size;
    const int B = 4, T = 1024, C = 1024, H = 8;
    const int BT = B * T;   // 4096
    const int HC = H * C;   // 8192

    const float* data = (const float*)d_in[0];
    const float* Wq = (const float*)d_in[1];
    const float* Wk = (const float*)d_in[2];
    const float* Wv = (const float*)d_in[3];
    float* out = (float*)d_out;

    // workspace (440 MiB of the 512 MiB ws)
    char* p = (char*)d_ws;
    const size_t nData = (size_t)BT * C;      // 4M
    const size_t nW = (size_t)H * C * C;      // 8M
    const size_t nAll = (size_t)BT * HC;      // 32M
    const size_t nS = (size_t)B * H * T * T;  // 32M
    u16* dataH = (u16*)p; p += nData * 2;     //   8 MiB
    u16* WqH = (u16*)p; p += nW * 2;          //  16 MiB
    u16* WkH = (u16*)p; p += nW * 2;          //  16 MiB
    u16* WvH = (u16*)p; p += nW * 2;          //  16 MiB
    u16* Qa = (u16*)p; p += nAll * 2;         //  64 MiB
    u16* Ka = (u16*)p; p += nAll * 2;         //  64 MiB
    u16* VTa = (u16*)p; p += nAll * 2;        //  64 MiB
    float* S = (float*)p; p += nS * 4;        // 128 MiB
    u16* P = (u16*)p; p += nS * 2;            //  64 MiB

    const dim3 blk256(256), blk512(512);
    const float inv_sqrt_c = 1.0f / 32.0f;

    cast_f32_f16<<<dim3((unsigned)(nData / 4 / 256)), blk256, 0, stream>>>(data, dataH, (int)(nData / 4));
    cast_f32_f16<<<dim3((unsigned)(nW / 4 / 256)), blk256, 0, stream>>>(Wq, WqH, (int)(nW / 4));
    cast_f32_f16<<<dim3((unsigned)(nW / 4 / 256)), blk256, 0, stream>>>(Wk, WkH, (int)(nW / 4));
    cast_f32_f16<<<dim3((unsigned)(nW / 4 / 256)), blk256, 0, stream>>>(Wv, WvH, (int)(nW / 4));

    // Q/K projections: [4096,1024] x [8192,1024]^T -> fp16 [4096,8192]
    gemm256<0><<<dim3(HC / 256, BT / 256, 1), blk512, 0, stream>>>(
        dataH, WqH, Qa, C, C, HC, 0, 0, 0, 0, 0, 0, C, 1.0f);
    gemm256<0><<<dim3(HC / 256, BT / 256, 1), blk512, 0, stream>>>(
        dataH, WkH, Ka, C, C, HC, 0, 0, 0, 0, 0, 0, C, 1.0f);

    // V^T directly: VT[z][c][t] = sum_k Wv[h][c][k] data[b][t][k]
    gemm256<0><<<dim3(T / 256, C / 256, B * H), blk512, 0, stream>>>(
        WvH, dataH, VTa, C, C, T,
        0, (long)C * C,               // A (Wv): h-stride
        (long)T * C, 0,               // B (data): b-stride
        (long)8 * C * T, (long)C * T, // C (VT): z-major
        C, 1.0f);

    // scores = Q K^T / sqrt(C), causal tiles, fp32
    gemm256<2><<<dim3(T / 256, T / 256, B * H), blk512, 0, stream>>>(
        Qa, Ka, S,
        HC, HC, T,
        (long)T * HC, C,
        (long)T * HC, C,
        (long)8 * T * T, (long)T * T,
        C, inv_sqrt_c);

    softmax_causal<<<dim3(T, B * H), blk256, 0, stream>>>(S, P);

    // out[b,t,h*C+d] = sum_s P[t,s] VT[d,s], causal K-limit
    gemm256<3><<<dim3(C / 256, T / 256, B * H), blk512, 0, stream>>>(
        P, VTa, out,
        T, T, HC,
        (long)8 * T * T, (long)T * T,
        (long)8 * C * T, (long)C * T,
        (long)T * HC, C,
        T, 1.0f);
}